// Round 1
// baseline (806.095 us; speedup 1.0000x reference)
//
#include <hip/hip_runtime.h>

// Problem constants
#define Mq   8192     // B*T
#define Hq   1024
#define Sq   1024
#define Tq   1024
#define Vq   5000
#define Vpad 5120     // V padded to multiple of 128 for GEMM2 tiling

typedef __bf16 bf16;
typedef bf16  bf16x8 __attribute__((ext_vector_type(8)));
typedef bf16  bf16x4 __attribute__((ext_vector_type(4)));
typedef float f32x4  __attribute__((ext_vector_type(4)));

typedef const __attribute__((address_space(1))) void* gas_t;
typedef __attribute__((address_space(3))) void*       sas_t;

__device__ __forceinline__ void async_copy16(const void* g, void* s) {
  // global -> LDS direct copy, 16B per lane; LDS dest = wave-uniform base + lane*16
  __builtin_amdgcn_global_load_lds((gas_t)g, (sas_t)s, 16, 0, 0);
}

// ---------------------------------------------------------------------------
// Kernel 1: fused x fp32 -> bf16 cast + p_gen = sigmoid(x @ Wg + bg)
// one block (256 thr) per row m; each thread handles 4 elements (float4)
// ---------------------------------------------------------------------------
__global__ __launch_bounds__(256) void pgen_cvt(
    const float* __restrict__ x, const float* __restrict__ Wg,
    const float* __restrict__ bg, bf16* __restrict__ xb,
    float* __restrict__ pgen) {
  const int m = blockIdx.x;
  const int t = threadIdx.x;
  float4 v = ((const float4*)(x + (size_t)m * Hq))[t];
  float4 g = ((const float4*)Wg)[t];
  float dot = v.x * g.x + v.y * g.y + v.z * g.z + v.w * g.w;
  bf16x4 o;
  o[0] = (bf16)v.x; o[1] = (bf16)v.y; o[2] = (bf16)v.z; o[3] = (bf16)v.w;
  ((bf16x4*)(xb + (size_t)m * Hq))[t] = o;
  #pragma unroll
  for (int off = 32; off; off >>= 1) dot += __shfl_down(dot, off, 64);
  __shared__ float red[4];
  if ((t & 63) == 0) red[t >> 6] = dot;
  __syncthreads();
  if (t == 0) {
    float s = red[0] + red[1] + red[2] + red[3] + bg[0];
    pgen[m] = 1.0f / (1.0f + __expf(-s));
  }
}

// ---------------------------------------------------------------------------
// Kernel 2/3: transpose + cast  W[K][Nin] fp32 -> WT[Npad][K] bf16 (zero pad)
// block (32,8), 32x32 tile
// ---------------------------------------------------------------------------
__global__ __launch_bounds__(256) void transpose_cvt(
    const float* __restrict__ W, bf16* __restrict__ WT,
    int K, int Nin, int Npad) {
  __shared__ float tile[32][33];
  const int nb = blockIdx.x * 32, kb = blockIdx.y * 32;
  const int tx = threadIdx.x, ty = threadIdx.y;
  #pragma unroll
  for (int i = 0; i < 32; i += 8) {
    int k = kb + ty + i, n = nb + tx;
    tile[ty + i][tx] = (n < Nin) ? W[(size_t)k * Nin + n] : 0.0f;
  }
  __syncthreads();
  #pragma unroll
  for (int i = 0; i < 32; i += 8) {
    int n = nb + ty + i, k = kb + tx;
    if (n < Npad) WT[(size_t)n * K + k] = (bf16)tile[tx][ty + i];
  }
}

// ---------------------------------------------------------------------------
// MFMA GEMM: C[M][N] = A[M][K] @ BT[N][K]^T  (+bias, epilogue per MODE)
// MODE 0: h = gelu_tanh(C + bias) -> bf16 out, stride N
// MODE 1: logits = C + bias -> fp32 out, stride Nstore, store only n < Nstore
// 128x128 tile, BK=32, 256 threads = 4 waves in 2x2, each wave 4x4 of 16x16x32
// ---------------------------------------------------------------------------
template <int MODE>
__global__ __launch_bounds__(256, 2) void gemm_mfma(
    const bf16* __restrict__ A, const bf16* __restrict__ BT,
    const float* __restrict__ bias, float* __restrict__ outF,
    bf16* __restrict__ outB, int M, int N, int K, int Nstore) {
  __shared__ bf16 As[128 * 32];
  __shared__ bf16 Bs[128 * 32];
  const int tid  = threadIdx.x;
  const int w    = tid >> 6;
  const int l    = tid & 63;
  const int quad = l >> 4;
  const int t16  = l & 15;
  const int wm   = (w >> 1) * 64;
  const int wn   = (w & 1) * 64;
  const int m0   = blockIdx.x * 128;
  const int n0   = blockIdx.y * 128;
  const int srow = l >> 2;         // 0..15 within the wave's 16-row chunk
  const int scol = (l & 3) * 8;    // k offset 0/8/16/24

  f32x4 acc[4][4] = {};

  for (int k0 = 0; k0 < K; k0 += 32) {
    __syncthreads();
    #pragma unroll
    for (int r = 0; r < 2; ++r) {
      const int chunk = r * 4 + w;            // 0..7, each chunk = 16 rows
      const int mrow  = chunk * 16 + srow;
      async_copy16(A  + (size_t)(m0 + mrow) * K + k0 + scol, As + chunk * 512);
      async_copy16(BT + (size_t)(n0 + mrow) * K + k0 + scol, Bs + chunk * 512);
    }
    __syncthreads();

    bf16x8 af[4], bfr[4];
    #pragma unroll
    for (int i = 0; i < 4; ++i)
      af[i] = *(const bf16x8*)(As + (wm + 16 * i + t16) * 32 + quad * 8);
    #pragma unroll
    for (int j = 0; j < 4; ++j)
      bfr[j] = *(const bf16x8*)(Bs + (wn + 16 * j + t16) * 32 + quad * 8);
    #pragma unroll
    for (int i = 0; i < 4; ++i)
      #pragma unroll
      for (int j = 0; j < 4; ++j)
        acc[i][j] = __builtin_amdgcn_mfma_f32_16x16x32_bf16(af[i], bfr[j], acc[i][j], 0, 0, 0);
  }

  // epilogue: D element (row m, col n): m = wm+16i+quad*4+r, n = wn+16j+t16
  #pragma unroll
  for (int i = 0; i < 4; ++i) {
    const int mg = m0 + wm + 16 * i + quad * 4;
    #pragma unroll
    for (int j = 0; j < 4; ++j) {
      const int ng = n0 + wn + 16 * j + t16;
      #pragma unroll
      for (int r = 0; r < 4; ++r) {
        float v = acc[i][j][r];
        if (MODE == 0) {
          v += bias[ng];
          float u = 0.7978845608028654f * (v + 0.044715f * v * v * v);
          float gl = 0.5f * v * (1.0f + tanhf(u));
          outB[(size_t)(mg + r) * N + ng] = (bf16)gl;
        } else {
          if (ng < Nstore) {
            v += bias[ng];
            outF[(size_t)(mg + r) * Nstore + ng] = v;
          }
        }
      }
    }
  }
}

// ---------------------------------------------------------------------------
// Kernel 6: in-place softmax over V, scaled by p_gen[m]
// ---------------------------------------------------------------------------
__global__ __launch_bounds__(256) void softmax_scale(
    float* __restrict__ out, const float* __restrict__ pgen, int V) {
  const size_t m = blockIdx.x;
  float* row = out + m * (size_t)V;
  __shared__ float buf[Vq];
  __shared__ float red[4];
  const int t = threadIdx.x;
  float mx = -1e30f;
  for (int i = t; i < V; i += 256) {
    float v = row[i];
    buf[i] = v;
    mx = fmaxf(mx, v);
  }
  #pragma unroll
  for (int off = 32; off; off >>= 1) mx = fmaxf(mx, __shfl_down(mx, off, 64));
  if ((t & 63) == 0) red[t >> 6] = mx;
  __syncthreads();
  mx = fmaxf(fmaxf(red[0], red[1]), fmaxf(red[2], red[3]));
  float s = 0.0f;
  for (int i = t; i < V; i += 256) {
    float e = __expf(buf[i] - mx);
    buf[i] = e;
    s += e;
  }
  #pragma unroll
  for (int off = 32; off; off >>= 1) s += __shfl_down(s, off, 64);
  __syncthreads();  // red[] reuse: all reads of max done before overwrite
  if ((t & 63) == 0) red[t >> 6] = s;
  __syncthreads();
  s = red[0] + red[1] + red[2] + red[3];
  const float scale = pgen[m] / s;
  for (int i = t; i < V; i += 256) row[i] = buf[i] * scale;
}

// ---------------------------------------------------------------------------
// Kernel 7: pointer/copy scatter: out[m][nodes[b][s]] += attn[m][s]*(1-pgen[m])
// ---------------------------------------------------------------------------
__global__ __launch_bounds__(256) void scatter_add(
    float* __restrict__ out, const float* __restrict__ attn,
    const int* __restrict__ nodes, const float* __restrict__ pgen) {
  const int m = blockIdx.x;
  const int b = m / Tq;
  const float p = 1.0f - pgen[m];
  const float* arow = attn + (size_t)m * Sq;
  const int* nrow = nodes + (size_t)b * Sq;
  float* orow = out + (size_t)m * Vq;
  for (int s = threadIdx.x; s < Sq; s += 256)
    atomicAdd(orow + nrow[s], arow[s] * p);
}

// ---------------------------------------------------------------------------
extern "C" void kernel_launch(void* const* d_in, const int* in_sizes, int n_in,
                              void* d_out, int out_size, void* d_ws, size_t ws_size,
                              hipStream_t stream) {
  const float* x    = (const float*)d_in[0];
  const float* attn = (const float*)d_in[1];
  const int*   nodes= (const int*)d_in[2];
  const float* Wg   = (const float*)d_in[3];
  const float* bg   = (const float*)d_in[4];
  const float* Wf   = (const float*)d_in[5];
  const float* bf_  = (const float*)d_in[6];
  const float* Wv   = (const float*)d_in[7];
  const float* bv   = (const float*)d_in[8];
  float* out = (float*)d_out;

  char* w = (char*)d_ws;
  bf16*  xb   = (bf16*)(w);                       // 8192*1024*2  = 16 MiB
  bf16*  h    = (bf16*)(w + 16777216);            // 8192*1024*2  = 16 MiB
  bf16*  WfT  = (bf16*)(w + 33554432);            // 1024*1024*2  =  2 MiB
  bf16*  WvT  = (bf16*)(w + 35651584);            // 5120*1024*2  = 10 MiB
  float* pgen = (float*)(w + 46137344);           // 8192*4

  pgen_cvt<<<Mq, 256, 0, stream>>>(x, Wg, bg, xb, pgen);
  transpose_cvt<<<dim3(Hq / 32, Hq / 32), dim3(32, 8), 0, stream>>>(Wf, WfT, Hq, Hq, Hq);
  transpose_cvt<<<dim3(Vpad / 32, Hq / 32), dim3(32, 8), 0, stream>>>(Wv, WvT, Hq, Vq, Vpad);
  gemm_mfma<0><<<dim3(Mq / 128, Hq / 128), 256, 0, stream>>>(
      xb, WfT, bf_, nullptr, h, Mq, Hq, Hq, Hq);
  gemm_mfma<1><<<dim3(Mq / 128, Vpad / 128), 256, 0, stream>>>(
      h, WvT, bv, out, nullptr, Mq, Vpad, Hq, Vq);
  softmax_scale<<<Mq, 256, 0, stream>>>(out, pgen, Vq);
  scatter_add<<<Mq, 256, 0, stream>>>(out, attn, nodes, pgen);
}

// Round 3
// 458.087 us; speedup vs baseline: 1.7597x; 1.7597x over previous
//
#include <hip/hip_runtime.h>

// Problem constants
#define Mq   8192     // B*T
#define Hq   1024
#define Sq   1024
#define Tq   1024
#define Vq   5000
#define Vpad 5120     // V padded to multiple of 128 for GEMM2 tiling

typedef __bf16 bf16;
typedef bf16  bf16x8 __attribute__((ext_vector_type(8)));
typedef bf16  bf16x4 __attribute__((ext_vector_type(4)));
typedef float f32x4  __attribute__((ext_vector_type(4)));

typedef const __attribute__((address_space(1))) void* gas_t;
typedef __attribute__((address_space(3))) void*       sas_t;

__device__ __forceinline__ void async_copy16(const void* g, void* s) {
  // global -> LDS direct copy, 16B per lane; LDS dest = wave-uniform base + lane*16
  __builtin_amdgcn_global_load_lds((gas_t)g, (sas_t)s, 16, 0, 0);
}

// ---------------------------------------------------------------------------
// Kernel 1: fused x fp32 -> bf16 cast + p_gen = sigmoid(x @ Wg + bg)
// one block (256 thr) per row m; each thread handles 4 elements (float4)
// ---------------------------------------------------------------------------
__global__ __launch_bounds__(256) void pgen_cvt(
    const float* __restrict__ x, const float* __restrict__ Wg,
    const float* __restrict__ bg, bf16* __restrict__ xb,
    float* __restrict__ pgen) {
  const int m = blockIdx.x;
  const int t = threadIdx.x;
  float4 v = ((const float4*)(x + (size_t)m * Hq))[t];
  float4 g = ((const float4*)Wg)[t];
  float dot = v.x * g.x + v.y * g.y + v.z * g.z + v.w * g.w;
  bf16x4 o;
  o[0] = (bf16)v.x; o[1] = (bf16)v.y; o[2] = (bf16)v.z; o[3] = (bf16)v.w;
  ((bf16x4*)(xb + (size_t)m * Hq))[t] = o;
  #pragma unroll
  for (int off = 32; off; off >>= 1) dot += __shfl_down(dot, off, 64);
  __shared__ float red[4];
  if ((t & 63) == 0) red[t >> 6] = dot;
  __syncthreads();
  if (t == 0) {
    float s = red[0] + red[1] + red[2] + red[3] + bg[0];
    pgen[m] = 1.0f / (1.0f + __expf(-s));
  }
}

// ---------------------------------------------------------------------------
// Kernel 2/3: transpose + cast  W[K][Nin] fp32 -> WT[Npad][K] bf16 (zero pad)
// block (32,8), 32x32 tile
// ---------------------------------------------------------------------------
__global__ __launch_bounds__(256) void transpose_cvt(
    const float* __restrict__ W, bf16* __restrict__ WT,
    int K, int Nin, int Npad) {
  __shared__ float tile[32][33];
  const int nb = blockIdx.x * 32, kb = blockIdx.y * 32;
  const int tx = threadIdx.x, ty = threadIdx.y;
  #pragma unroll
  for (int i = 0; i < 32; i += 8) {
    int k = kb + ty + i, n = nb + tx;
    tile[ty + i][tx] = (n < Nin) ? W[(size_t)k * Nin + n] : 0.0f;
  }
  __syncthreads();
  #pragma unroll
  for (int i = 0; i < 32; i += 8) {
    int n = nb + ty + i, k = kb + tx;
    if (n < Npad) WT[(size_t)n * K + k] = (bf16)tile[tx][ty + i];
  }
}

// ---------------------------------------------------------------------------
// MFMA GEMM: C[M][N] = A[M][K] @ BT[N][K]^T  (+bias, epilogue per MODE)
// MODE 0: h = gelu_tanh(C + bias) -> bf16 out, stride N
// MODE 1: logits = C + bias -> fp32 out, stride Nstore, store only n < Nstore
// 128x128 tile, BK=32, 256 threads = 4 waves in 2x2, each wave 4x4 of 16x16x32
// ---------------------------------------------------------------------------
template <int MODE>
__global__ __launch_bounds__(256, 2) void gemm_mfma(
    const bf16* __restrict__ A, const bf16* __restrict__ BT,
    const float* __restrict__ bias, float* __restrict__ outF,
    bf16* __restrict__ outB, int M, int N, int K, int Nstore) {
  __shared__ bf16 As[128 * 32];
  __shared__ bf16 Bs[128 * 32];
  const int tid  = threadIdx.x;
  const int w    = tid >> 6;
  const int l    = tid & 63;
  const int quad = l >> 4;
  const int t16  = l & 15;
  const int wm   = (w >> 1) * 64;
  const int wn   = (w & 1) * 64;
  const int m0   = blockIdx.x * 128;
  const int n0   = blockIdx.y * 128;
  const int srow = l >> 2;         // 0..15 within the wave's 16-row chunk
  const int scol = (l & 3) * 8;    // k offset 0/8/16/24

  f32x4 acc[4][4] = {};

  for (int k0 = 0; k0 < K; k0 += 32) {
    __syncthreads();
    #pragma unroll
    for (int r = 0; r < 2; ++r) {
      const int chunk = r * 4 + w;            // 0..7, each chunk = 16 rows
      const int mrow  = chunk * 16 + srow;
      async_copy16(A  + (size_t)(m0 + mrow) * K + k0 + scol, As + chunk * 512);
      async_copy16(BT + (size_t)(n0 + mrow) * K + k0 + scol, Bs + chunk * 512);
    }
    __syncthreads();

    bf16x8 af[4], bfr[4];
    #pragma unroll
    for (int i = 0; i < 4; ++i)
      af[i] = *(const bf16x8*)(As + (wm + 16 * i + t16) * 32 + quad * 8);
    #pragma unroll
    for (int j = 0; j < 4; ++j)
      bfr[j] = *(const bf16x8*)(Bs + (wn + 16 * j + t16) * 32 + quad * 8);
    #pragma unroll
    for (int i = 0; i < 4; ++i)
      #pragma unroll
      for (int j = 0; j < 4; ++j)
        acc[i][j] = __builtin_amdgcn_mfma_f32_16x16x32_bf16(af[i], bfr[j], acc[i][j], 0, 0, 0);
  }

  // epilogue: D element (row m, col n): m = wm+16i+quad*4+r, n = wn+16j+t16
  #pragma unroll
  for (int i = 0; i < 4; ++i) {
    const int mg = m0 + wm + 16 * i + quad * 4;
    #pragma unroll
    for (int j = 0; j < 4; ++j) {
      const int ng = n0 + wn + 16 * j + t16;
      #pragma unroll
      for (int r = 0; r < 4; ++r) {
        float v = acc[i][j][r];
        if (MODE == 0) {
          v += bias[ng];
          float u = 0.7978845608028654f * (v + 0.044715f * v * v * v);
          float gl = 0.5f * v * (1.0f + tanhf(u));
          outB[(size_t)(mg + r) * N + ng] = (bf16)gl;
        } else {
          if (ng < Nstore) {
            v += bias[ng];
            outF[(size_t)(mg + r) * Nstore + ng] = v;
          }
        }
      }
    }
  }
}

// ---------------------------------------------------------------------------
// Kernel 6 (fused): softmax over V, *p_gen, then pointer/copy scatter via LDS
// atomics, single global write. One block (256 thr) per row m.
//   out[m][v] = softmax(logits[m])[v]*pgen[m]  (+)  sum_{s:nodes[b][s]=v} attn[m][s]*(1-pgen[m])
// ---------------------------------------------------------------------------
__global__ __launch_bounds__(256) void softmax_scatter(
    float* __restrict__ out, const float* __restrict__ pgen,
    const float* __restrict__ attn, const int* __restrict__ nodes) {
  const int m = blockIdx.x;
  const int b = m / Tq;
  float* row = out + (size_t)m * Vq;
  __shared__ float buf[Vq];
  __shared__ float red[4];
  const int t = threadIdx.x;

  // load logits (float4) + rowmax
  float mx = -1e30f;
  float4* buf4 = (float4*)buf;
  const float4* rowLd = (const float4*)row;
  float4* rowSt = (float4*)row;
  for (int i = t; i < Vq / 4; i += 256) {
    float4 v = rowLd[i];
    buf4[i] = v;
    mx = fmaxf(fmaxf(v.x, v.y), fmaxf(fmaxf(v.z, v.w), mx));
  }
  #pragma unroll
  for (int off = 32; off; off >>= 1) mx = fmaxf(mx, __shfl_down(mx, off, 64));
  if ((t & 63) == 0) red[t >> 6] = mx;
  __syncthreads();
  mx = fmaxf(fmaxf(red[0], red[1]), fmaxf(red[2], red[3]));

  // exp + sum
  float s = 0.0f;
  for (int i = t; i < Vq; i += 256) {
    float e = __expf(buf[i] - mx);
    buf[i] = e;
    s += e;
  }
  #pragma unroll
  for (int off = 32; off; off >>= 1) s += __shfl_down(s, off, 64);
  __syncthreads();  // all reads of red[] (max) done before overwrite
  if ((t & 63) == 0) red[t >> 6] = s;
  __syncthreads();
  s = red[0] + red[1] + red[2] + red[3];

  const float pg = pgen[m];
  const float scale = pg / s;
  for (int i = t; i < Vq; i += 256) buf[i] *= scale;
  __syncthreads();

  // pointer/copy scatter into LDS (ds_add_f32 — no global RMW)
  const float pc = 1.0f - pg;
  const float* arow = attn + (size_t)m * Sq;
  const int* nrow = nodes + (size_t)b * Sq;
  for (int sIdx = t; sIdx < Sq; sIdx += 256)
    atomicAdd(&buf[nrow[sIdx]], arow[sIdx] * pc);
  __syncthreads();

  // single coalesced write
  for (int i = t; i < Vq / 4; i += 256) {
    rowSt[i] = buf4[i];
  }
}

// ---------------------------------------------------------------------------
extern "C" void kernel_launch(void* const* d_in, const int* in_sizes, int n_in,
                              void* d_out, int out_size, void* d_ws, size_t ws_size,
                              hipStream_t stream) {
  const float* x    = (const float*)d_in[0];
  const float* attn = (const float*)d_in[1];
  const int*   nodes= (const int*)d_in[2];
  const float* Wg   = (const float*)d_in[3];
  const float* bg   = (const float*)d_in[4];
  const float* Wf   = (const float*)d_in[5];
  const float* bf_  = (const float*)d_in[6];
  const float* Wv   = (const float*)d_in[7];
  const float* bv   = (const float*)d_in[8];
  float* out = (float*)d_out;

  char* w = (char*)d_ws;
  bf16*  xb   = (bf16*)(w);                       // 8192*1024*2  = 16 MiB
  bf16*  h    = (bf16*)(w + 16777216);            // 8192*1024*2  = 16 MiB
  bf16*  WfT  = (bf16*)(w + 33554432);            // 1024*1024*2  =  2 MiB
  bf16*  WvT  = (bf16*)(w + 35651584);            // 5120*1024*2  = 10 MiB
  float* pgen = (float*)(w + 46137344);           // 8192*4

  pgen_cvt<<<Mq, 256, 0, stream>>>(x, Wg, bg, xb, pgen);
  transpose_cvt<<<dim3(Hq / 32, Hq / 32), dim3(32, 8), 0, stream>>>(Wf, WfT, Hq, Hq, Hq);
  transpose_cvt<<<dim3(Vpad / 32, Hq / 32), dim3(32, 8), 0, stream>>>(Wv, WvT, Hq, Vq, Vpad);
  gemm_mfma<0><<<dim3(Mq / 128, Hq / 128), 256, 0, stream>>>(
      xb, WfT, bf_, nullptr, h, Mq, Hq, Hq, Hq);
  gemm_mfma<1><<<dim3(Mq / 128, Vpad / 128), 256, 0, stream>>>(
      h, WvT, bv, out, nullptr, Mq, Vpad, Hq, Vq);
  softmax_scatter<<<Mq, 256, 0, stream>>>(out, pgen, attn, nodes);
}

// Round 4
// 420.774 us; speedup vs baseline: 1.9157x; 1.0887x over previous
//
#include <hip/hip_runtime.h>

// Problem constants
#define Mq   8192     // B*T
#define Hq   1024
#define Sq   1024
#define Tq   1024
#define Vq   5000
#define Vpad 5120     // V padded to multiple of 128 for GEMM2 tiling

typedef __bf16 bf16;
typedef bf16  bf16x8 __attribute__((ext_vector_type(8)));
typedef bf16  bf16x4 __attribute__((ext_vector_type(4)));
typedef float f32x4  __attribute__((ext_vector_type(4)));

typedef const __attribute__((address_space(1))) void* gas_t;
typedef __attribute__((address_space(3))) void*       sas_t;

__device__ __forceinline__ void async_copy16(const void* g, void* s) {
  __builtin_amdgcn_global_load_lds((gas_t)g, (sas_t)s, 16, 0, 0);
}

// ---------------------------------------------------------------------------
// Kernel 1: fused x fp32 -> bf16 cast + p_gen = sigmoid(x @ Wg + bg)
// ---------------------------------------------------------------------------
__global__ __launch_bounds__(256) void pgen_cvt(
    const float* __restrict__ x, const float* __restrict__ Wg,
    const float* __restrict__ bg, bf16* __restrict__ xb,
    float* __restrict__ pgen) {
  const int m = blockIdx.x;
  const int t = threadIdx.x;
  float4 v = ((const float4*)(x + (size_t)m * Hq))[t];
  float4 g = ((const float4*)Wg)[t];
  float dot = v.x * g.x + v.y * g.y + v.z * g.z + v.w * g.w;
  bf16x4 o;
  o[0] = (bf16)v.x; o[1] = (bf16)v.y; o[2] = (bf16)v.z; o[3] = (bf16)v.w;
  ((bf16x4*)(xb + (size_t)m * Hq))[t] = o;
  #pragma unroll
  for (int off = 32; off; off >>= 1) dot += __shfl_down(dot, off, 64);
  __shared__ float red[4];
  if ((t & 63) == 0) red[t >> 6] = dot;
  __syncthreads();
  if (t == 0) {
    float s = red[0] + red[1] + red[2] + red[3] + bg[0];
    pgen[m] = 1.0f / (1.0f + __expf(-s));
  }
}

// ---------------------------------------------------------------------------
// Kernel 2/3: transpose + cast  W[K][Nin] fp32 -> WT[Npad][K] bf16 (zero pad)
// ---------------------------------------------------------------------------
__global__ __launch_bounds__(256) void transpose_cvt(
    const float* __restrict__ W, bf16* __restrict__ WT,
    int K, int Nin, int Npad) {
  __shared__ float tile[32][33];
  const int nb = blockIdx.x * 32, kb = blockIdx.y * 32;
  const int tx = threadIdx.x, ty = threadIdx.y;
  #pragma unroll
  for (int i = 0; i < 32; i += 8) {
    int k = kb + ty + i, n = nb + tx;
    tile[ty + i][tx] = (n < Nin) ? W[(size_t)k * Nin + n] : 0.0f;
  }
  __syncthreads();
  #pragma unroll
  for (int i = 0; i < 32; i += 8) {
    int n = nb + ty + i, k = kb + tx;
    if (n < Npad) WT[(size_t)n * K + k] = (bf16)tile[tx][ty + i];
  }
}

// ---------------------------------------------------------------------------
// MFMA GEMM: C = A @ BT^T (+bias, epilogue per MODE)
// MODE 0: h = gelu_tanh(C+bias) -> bf16, stride N
// MODE 1: e = exp(C+bias)       -> bf16, stride Nstore (cols >= Nstore skipped)
// MODE 2: e = exp(C+bias)       -> fp32, stride Nstore (fallback, into d_out)
// 128x128 tile, BK=32, 4 waves 2x2, each wave 4x4 of 16x16x32 bf16 MFMA
// ---------------------------------------------------------------------------
template <int MODE>
__global__ __launch_bounds__(256, 2) void gemm_mfma(
    const bf16* __restrict__ A, const bf16* __restrict__ BT,
    const float* __restrict__ bias, float* __restrict__ outF,
    bf16* __restrict__ outB, int M, int N, int K, int Nstore) {
  __shared__ bf16 As[128 * 32];
  __shared__ bf16 Bs[128 * 32];
  const int tid  = threadIdx.x;
  const int w    = tid >> 6;
  const int l    = tid & 63;
  const int quad = l >> 4;
  const int t16  = l & 15;
  const int wm   = (w >> 1) * 64;
  const int wn   = (w & 1) * 64;
  const int m0   = blockIdx.x * 128;
  const int n0   = blockIdx.y * 128;
  const int srow = l >> 2;
  const int scol = (l & 3) * 8;

  f32x4 acc[4][4] = {};

  for (int k0 = 0; k0 < K; k0 += 32) {
    __syncthreads();
    #pragma unroll
    for (int r = 0; r < 2; ++r) {
      const int chunk = r * 4 + w;
      const int mrow  = chunk * 16 + srow;
      async_copy16(A  + (size_t)(m0 + mrow) * K + k0 + scol, As + chunk * 512);
      async_copy16(BT + (size_t)(n0 + mrow) * K + k0 + scol, Bs + chunk * 512);
    }
    __syncthreads();

    bf16x8 af[4], bfr[4];
    #pragma unroll
    for (int i = 0; i < 4; ++i)
      af[i] = *(const bf16x8*)(As + (wm + 16 * i + t16) * 32 + quad * 8);
    #pragma unroll
    for (int j = 0; j < 4; ++j)
      bfr[j] = *(const bf16x8*)(Bs + (wn + 16 * j + t16) * 32 + quad * 8);
    #pragma unroll
    for (int i = 0; i < 4; ++i)
      #pragma unroll
      for (int j = 0; j < 4; ++j)
        acc[i][j] = __builtin_amdgcn_mfma_f32_16x16x32_bf16(af[i], bfr[j], acc[i][j], 0, 0, 0);
  }

  // hoist bias: depends only on j (col ng)
  float bj[4];
  #pragma unroll
  for (int j = 0; j < 4; ++j) {
    const int ng = n0 + wn + 16 * j + t16;
    bj[j] = (MODE == 0 || ng < Nstore) ? bias[ng] : 0.0f;
  }

  // epilogue: D element (row m, col n): m = wm+16i+quad*4+r, n = wn+16j+t16
  #pragma unroll
  for (int i = 0; i < 4; ++i) {
    const int mg = m0 + wm + 16 * i + quad * 4;
    #pragma unroll
    for (int j = 0; j < 4; ++j) {
      const int ng = n0 + wn + 16 * j + t16;
      #pragma unroll
      for (int r = 0; r < 4; ++r) {
        float v = acc[i][j][r] + bj[j];
        if (MODE == 0) {
          // gelu (tanh approx), tanh via __expf: tanh(u) = 1 - 2/(e^{2u}+1)
          float u  = 0.7978845608028654f * (v + 0.044715f * v * v * v);
          float e2 = __expf(2.0f * u);
          float th = 1.0f - 2.0f / (e2 + 1.0f);
          outB[(size_t)(mg + r) * N + ng] = (bf16)(0.5f * v * (1.0f + th));
        } else if (MODE == 1) {
          if (ng < Nstore)
            outB[(size_t)(mg + r) * Nstore + ng] = (bf16)__expf(v);
        } else {
          if (ng < Nstore)
            outF[(size_t)(mg + r) * Nstore + ng] = __expf(v);
        }
      }
    }
  }
}

// ---------------------------------------------------------------------------
// Finalize: out[m][v] = e[m][v] * pg/S  +  sum_{s:nodes[b][s]=v} attn[m][s]*(1-pg)
// S = sum_v e[m][v]. One block per row m. ET = bf16 (ws path) or float
// (fallback: e IS d_out, in-place per-row — safe, block m only touches row m).
// ---------------------------------------------------------------------------
template <typename ET>
__global__ __launch_bounds__(256) void finalize(
    float* __restrict__ out, const ET* __restrict__ e,
    const float* __restrict__ pgen, const float* __restrict__ attn,
    const int* __restrict__ nodes) {
  const int m = blockIdx.x;
  const int b = m / Tq;
  const int t = threadIdx.x;
  __shared__ float buf[Vq];
  __shared__ float red[4];

  // pass 1: load e -> LDS (fp32) + running sum
  float s = 0.0f;
  const ET* erow = e + (size_t)m * Vq;
  if constexpr (sizeof(ET) == 2) {
    const bf16x8* e8 = (const bf16x8*)erow;
    for (int i = t; i < Vq / 8; i += 256) {
      bf16x8 v = e8[i];
      #pragma unroll
      for (int k = 0; k < 8; ++k) {
        float f = (float)v[k];
        buf[i * 8 + k] = f;
        s += f;
      }
    }
  } else {
    const float4* e4 = (const float4*)erow;
    for (int i = t; i < Vq / 4; i += 256) {
      float4 v = e4[i];
      buf[i * 4 + 0] = v.x; buf[i * 4 + 1] = v.y;
      buf[i * 4 + 2] = v.z; buf[i * 4 + 3] = v.w;
      s += (v.x + v.y) + (v.z + v.w);
    }
  }
  #pragma unroll
  for (int off = 32; off; off >>= 1) s += __shfl_down(s, off, 64);
  if ((t & 63) == 0) red[t >> 6] = s;
  __syncthreads();
  s = red[0] + red[1] + red[2] + red[3];

  const float pg    = pgen[m];
  const float scale = pg / s;                 // applied at write-out
  const float coef  = (1.0f - pg) / scale;    // pre-divide scatter mass

  // pass 2: scatter attn mass into LDS (ds_add_f32)
  const float* arow = attn + (size_t)m * Sq;
  const int*   nrow = nodes + (size_t)b * Sq;
  for (int sIdx = t; sIdx < Sq; sIdx += 256)
    atomicAdd(&buf[nrow[sIdx]], arow[sIdx] * coef);
  __syncthreads();

  // pass 3: scaled coalesced write
  float4* o4 = (float4*)(out + (size_t)m * Vq);
  const float4* b4 = (const float4*)buf;
  for (int i = t; i < Vq / 4; i += 256) {
    float4 v = b4[i];
    v.x *= scale; v.y *= scale; v.z *= scale; v.w *= scale;
    o4[i] = v;
  }
}

// ---------------------------------------------------------------------------
extern "C" void kernel_launch(void* const* d_in, const int* in_sizes, int n_in,
                              void* d_out, int out_size, void* d_ws, size_t ws_size,
                              hipStream_t stream) {
  const float* x    = (const float*)d_in[0];
  const float* attn = (const float*)d_in[1];
  const int*   nodes= (const int*)d_in[2];
  const float* Wg   = (const float*)d_in[3];
  const float* bg   = (const float*)d_in[4];
  const float* Wf   = (const float*)d_in[5];
  const float* bf_  = (const float*)d_in[6];
  const float* Wv   = (const float*)d_in[7];
  const float* bv   = (const float*)d_in[8];
  float* out = (float*)d_out;

  char* w = (char*)d_ws;

  // big-ws layout: e overlaps xb (xb dead once gemm1 completes; stream-ordered)
  //   eB   [0,          81,920,000)   8192*5000 bf16
  //   xb   [0,          16,777,216)   (lifetime: pgen_cvt .. gemm1)
  //   hB   [81,920,000, 98,697,216)   8192*1024 bf16
  //   WfT  [98,697,216, 100,794,368)  1024*1024 bf16
  //   WvT  [100,794,368,111,280,128)  5120*1024 bf16
  //   pgen [111,280,128,111,312,896)  8192 fp32
  const size_t NEED = 111312896ull;
  const bool big = ws_size >= NEED;

  if (big) {
    bf16*  eB   = (bf16*)(w);
    bf16*  xb   = (bf16*)(w);
    bf16*  hB   = (bf16*)(w + 81920000ull);
    bf16*  WfT  = (bf16*)(w + 98697216ull);
    bf16*  WvT  = (bf16*)(w + 100794368ull);
    float* pgen = (float*)(w + 111280128ull);

    pgen_cvt<<<Mq, 256, 0, stream>>>(x, Wg, bg, xb, pgen);
    transpose_cvt<<<dim3(Hq / 32, Hq / 32), dim3(32, 8), 0, stream>>>(Wf, WfT, Hq, Hq, Hq);
    transpose_cvt<<<dim3(Vpad / 32, Hq / 32), dim3(32, 8), 0, stream>>>(Wv, WvT, Hq, Vq, Vpad);
    gemm_mfma<0><<<dim3(Mq / 128, Hq / 128), 256, 0, stream>>>(
        xb, WfT, bf_, nullptr, hB, Mq, Hq, Hq, Hq);
    gemm_mfma<1><<<dim3(Mq / 128, Vpad / 128), 256, 0, stream>>>(
        hB, WvT, bv, nullptr, eB, Mq, Vpad, Hq, Vq);
    finalize<bf16><<<Mq, 256, 0, stream>>>(out, eB, pgen, attn, nodes);
  } else {
    // fallback: e fp32 in d_out, finalize in-place
    bf16*  xb   = (bf16*)(w);                       // 16 MiB
    bf16*  hB   = (bf16*)(w + 16777216);            // 16 MiB
    bf16*  WfT  = (bf16*)(w + 33554432);            //  2 MiB
    bf16*  WvT  = (bf16*)(w + 35651584);            // 10 MiB
    float* pgen = (float*)(w + 46137344);           // 32 KiB

    pgen_cvt<<<Mq, 256, 0, stream>>>(x, Wg, bg, xb, pgen);
    transpose_cvt<<<dim3(Hq / 32, Hq / 32), dim3(32, 8), 0, stream>>>(Wf, WfT, Hq, Hq, Hq);
    transpose_cvt<<<dim3(Vpad / 32, Hq / 32), dim3(32, 8), 0, stream>>>(Wv, WvT, Hq, Vq, Vpad);
    gemm_mfma<0><<<dim3(Mq / 128, Hq / 128), 256, 0, stream>>>(
        xb, WfT, bf_, nullptr, hB, Mq, Hq, Hq, Hq);
    gemm_mfma<2><<<dim3(Mq / 128, Vpad / 128), 256, 0, stream>>>(
        hB, WvT, bv, out, nullptr, Mq, Vpad, Hq, Vq);
    finalize<float><<<Mq, 256, 0, stream>>>(out, out, pgen, attn, nodes);
  }
}